// Round 3
// baseline (3256.702 us; speedup 1.0000x reference)
//
#include <hip/hip_runtime.h>
#include <math.h>

#define BB 16
#define SS 64
#define MM 2048
#define DD 256
#define TOPK 8
#define NCH 16
#define CHR 128            // rows per chunk
#define SCALE 0.0625f      // 1/sqrt(256)

__device__ __forceinline__ float wave_sum(float p) {
    for (int o = 32; o; o >>= 1) p += __shfl_xor(p, o);
    return p;
}

__device__ __forceinline__ void wave_argmax(float& v, int& i) {
    for (int o = 32; o; o >>= 1) {
        float ov = __shfl_xor(v, o);
        int oi = __shfl_xor(i, o);
        if (ov > v || (ov == v && oi < i)) { v = ov; i = oi; }
    }
}

// generic 32x32-tiled transpose: dst[c][r] = src[r][c]; grid=(C/32, R/32), block=256
__global__ __launch_bounds__(256) void k_tr(const float* __restrict__ src, float* __restrict__ dst,
                                            int sld, int dld) {
    __shared__ float ts[32][33];
    int c0 = blockIdx.x * 32, r0 = blockIdx.y * 32;
    int xx = threadIdx.x & 31, yy = threadIdx.x >> 5;
    for (int i = 0; i < 4; ++i)
        ts[yy + 8 * i][xx] = src[(size_t)(r0 + yy + 8 * i) * sld + c0 + xx];
    __syncthreads();
    for (int i = 0; i < 4; ++i)
        dst[(size_t)(c0 + yy + 8 * i) * dld + r0 + xx] = ts[xx][yy + 8 * i];
}

// C[i][j] = sum_d A[i][d]*B[d][j] (+bias[j]); optional c0o[i] = Arow . bkv. grid = rows
__global__ __launch_bounds__(256) void k_gemv(const float* __restrict__ A, const float* __restrict__ B,
                                              const float* __restrict__ bias, float* __restrict__ C,
                                              const float* __restrict__ bkv, float* __restrict__ c0o) {
    const int i = blockIdx.x, tid = threadIdx.x;
    __shared__ float as[DD];
    as[tid] = A[(size_t)i * DD + tid];
    __syncthreads();
    float a0 = bias ? bias[tid] : 0.f, a1 = 0.f;
#pragma unroll 4
    for (int d = 0; d < DD; d += 2) {
        a0 = fmaf(as[d],     B[(size_t)d * DD + tid],       a0);
        a1 = fmaf(as[d + 1], B[(size_t)(d + 1) * DD + tid], a1);
    }
    C[(size_t)i * DD + tid] = a0 + a1;
    if (c0o && tid < 64) {
        float4 a4 = ((const float4*)as)[tid];
        float4 b4 = ((const float4*)bkv)[tid];
        float p = wave_sum(a4.x * b4.x + a4.y * b4.y + a4.z * b4.z + a4.w * b4.w);
        if (tid == 0) c0o[i] = p;
    }
}

// F[j][d] = sum_k Wu[j][256+k]*Wv[k][d];  cb[j] = sum_k bv[k]*Wu[j][256+k]. grid=256
__global__ __launch_bounds__(256) void k_fuse(const float* __restrict__ Wu, const float* __restrict__ Wv,
                                              const float* __restrict__ bv, float* __restrict__ F,
                                              float* __restrict__ cb) {
    const int j = blockIdx.x, tid = threadIdx.x;
    const float* wuh = Wu + (size_t)j * (2 * DD) + DD;
    float a0 = 0.f, a1 = 0.f;
#pragma unroll 4
    for (int k = 0; k < DD; k += 2) {
        a0 = fmaf(wuh[k],     Wv[(size_t)k * DD + tid],       a0);
        a1 = fmaf(wuh[k + 1], Wv[(size_t)(k + 1) * DD + tid], a1);
    }
    F[(size_t)j * DD + tid] = a0 + a1;
    if (tid < 64) {
        float4 b4 = ((const float4*)bv)[tid];
        float4 w4 = ((const float4*)wuh)[tid];
        float p = wave_sum(b4.x * w4.x + b4.y * w4.y + b4.z * w4.z + b4.w * w4.w);
        if (tid == 0) cb[j] = p;
    }
}

__global__ __launch_bounds__(256) void k_zero(int* __restrict__ p, int n) {
    int i = blockIdx.x * 256 + threadIdx.x;
    if (i < n) p[i] = 0;
}

__device__ __forceinline__ void batch_barrier(unsigned* c, unsigned target) {
    __syncthreads();
    if (threadIdx.x == 0) {
        __hip_atomic_fetch_add(c, 1u, __ATOMIC_ACQ_REL, __HIP_MEMORY_SCOPE_AGENT);
        while (__hip_atomic_load(c, __ATOMIC_ACQUIRE, __HIP_MEMORY_SCOPE_AGENT) < target)
            __builtin_amdgcn_s_sleep(2);
    }
    __syncthreads();
}

__global__ __launch_bounds__(256) void k_persist(
    const float* __restrict__ x, const float* __restrict__ memory0,
    const float* __restrict__ memT, const float* __restrict__ QK,
    const float* __restrict__ c0All, const float* __restrict__ GXU,
    const float* __restrict__ F, const float* __restrict__ cb,
    const float* __restrict__ Wv, const float* __restrict__ bv,
    float* __restrict__ dval, float* __restrict__ pe, float* __restrict__ pam,
    float* __restrict__ candV, int* __restrict__ candI, float* __restrict__ gWork,
    int* __restrict__ flagslot, int* __restrict__ listChunk,
    int* __restrict__ chunkCnt, int* __restrict__ slotCnt,
    unsigned* __restrict__ ctr, float* __restrict__ out) {
    const int c = blockIdx.x & 15, b = blockIdx.x >> 4;
    const int tid = threadIdx.x, w = tid >> 6, lane = tid & 63;
    __shared__ float qks[DD], xs[DD], amS[DD];
    __shared__ float es[CHR];
    __shared__ float pPart[4][64];
    __shared__ float peS[16];
    __shared__ int topI[TOPK];
    __shared__ int slotK, wasD;
    unsigned* myctr = ctr + b * 16;     // padded: 64B apart per batch
    unsigned barTarget = 0;

    for (int t = 0; t < SS; ++t) {
        const int bt = (b << 6) + t;
        qks[tid] = QK[(size_t)bt * DD + tid];
        xs[tid] = x[(size_t)bt * DD + tid];
        const float c0v = c0All[bt];
        const int nd = chunkCnt[b * 16 + c];
        __syncthreads();

        // ---- phase 1: scores over my 128 rows via memT (qk . memory0[m]) ----
        {
            const int h = w & 1, dh = w >> 1;
            const float* mptr = memT + (size_t)(dh * 128) * MM + c * CHR + h * 64 + lane;
            const float* qp = qks + dh * 128;
            float a0 = 0.f, a1 = 0.f, a2 = 0.f, a3 = 0.f;
#pragma unroll 8
            for (int d = 0; d < 128; d += 4) {
                a0 = fmaf(qp[d],     mptr[(size_t)d * MM],       a0);
                a1 = fmaf(qp[d + 1], mptr[(size_t)(d + 1) * MM], a1);
                a2 = fmaf(qp[d + 2], mptr[(size_t)(d + 2) * MM], a2);
                a3 = fmaf(qp[d + 3], mptr[(size_t)(d + 3) * MM], a3);
            }
            pPart[w][lane] = (a0 + a1) + (a2 + a3);
        }
        __syncthreads();
        if (tid < CHR) {
            int hh = tid >> 6, l = tid & 63;
            float s = pPart[hh][l] + pPart[hh + 2][l];
            es[tid] = expf((s + c0v) * SCALE);
        }
        __syncthreads();
        // dirty-row replacements: e = exp((qk . cur[m] + c0) * scale)
        for (int i = w; i < nd; i += 4) {
            int packed = listChunk[(b * 16 + c) * CHR + i];
            int rl = packed & 127, slot = packed >> 7;
            float4 dv = ((const float4*)(dval + ((size_t)b * 512 + slot) * DD))[lane];
            float4 q4 = ((const float4*)qks)[lane];
            float p = wave_sum(dv.x * q4.x + dv.y * q4.y + dv.z * q4.z + dv.w * q4.w);
            if (lane == 0) es[rl] = expf((p + c0v) * SCALE);
        }
        __syncthreads();

        if (w == 0) {                    // denom partial
            float v = es[lane] + es[lane + 64];
            float p = wave_sum(v);
            if (lane == 0) pe[b * 16 + c] = p;
        } else if (w == 1) {             // chunk-local top-8 candidates
            float v0 = es[lane], v1 = es[lane + 64];
            int i0 = lane, i1 = lane + 64;
            for (int k = 0; k < TOPK; ++k) {
                float bb = v0; int bi = i0;
                if (v1 > v0 || (v1 == v0 && i1 < i0)) { bb = v1; bi = i1; }
                wave_argmax(bb, bi);
                if (lane == 0) {
                    candV[(b * 16 + c) * TOPK + k] = bb;
                    candI[(b * 16 + c) * TOPK + k] = c * CHR + bi;
                }
                if (i0 == bi) v0 = -1e30f;
                if (i1 == bi) v1 = -1e30f;
            }
        } else {                         // weighted-mem partial: sum e*cur over chunk
            int d0 = (w - 2) * 64 + lane;            // covers [0,128)
            const float* m0 = memory0 + (size_t)c * CHR * DD;
            float p0 = 0.f, p1 = 0.f;
#pragma unroll 4
            for (int r = 0; r < CHR; ++r) {
                float e = es[r];
                p0 = fmaf(e, m0[(size_t)r * DD + d0], p0);
                p1 = fmaf(e, m0[(size_t)r * DD + d0 + 128], p1);
            }
            for (int i = 0; i < nd; ++i) {
                int packed = listChunk[(b * 16 + c) * CHR + i];
                int rl = packed & 127, slot = packed >> 7;
                float e = es[rl];
                const float* dv = dval + ((size_t)b * 512 + slot) * DD;
                const float* mr = m0 + (size_t)rl * DD;
                p0 += e * (dv[d0] - mr[d0]);
                p1 += e * (dv[d0 + 128] - mr[d0 + 128]);
            }
            pam[(size_t)(b * 16 + c) * DD + d0] = p0;
            pam[(size_t)(b * 16 + c) * DD + d0 + 128] = p1;
        }

        barTarget += 16;
        batch_barrier(myctr, barTarget);             // barrier A

        // ---- phase 2: am, gate slice, mem_out slice, top-8 merge ----
        if (tid < 16) peS[tid] = pe[b * 16 + tid];
        __syncthreads();
        float tot = 0.f;
#pragma unroll
        for (int i2 = 0; i2 < 16; ++i2) tot += peS[i2];
        float a = 0.f;
#pragma unroll
        for (int p2 = 0; p2 < 16; ++p2) a += pam[(size_t)(b * 16 + p2) * DD + tid];
        amS[tid] = a / tot;
        __syncthreads();

        if (w == 0) {                    // merge 128 candidates -> global top-8
            float v0 = candV[b * 128 + lane], v1 = candV[b * 128 + 64 + lane];
            int i0 = candI[b * 128 + lane], i1 = candI[b * 128 + 64 + lane];
            for (int k = 0; k < TOPK; ++k) {
                float bb = v0; int bi = i0;
                if (v1 > v0 || (v1 == v0 && i1 < i0)) { bb = v1; bi = i1; }
                wave_argmax(bb, bi);
                if (lane == 0) topI[k] = bi;
                if (i0 == bi) v0 = -1e30f;
                if (i1 == bi) v1 = -1e30f;
            }
        } else {
            float4 a4 = ((const float4*)amS)[lane];
            for (int tt = w - 1; tt < 32; tt += 3) {
                int j = c * 16 + (tt & 15);
                if (tt < 16) {           // gate[j] = sigmoid(gxu + am.F[j] + cb[j])
                    float4 f4 = ((const float4*)(F + (size_t)j * DD))[lane];
                    float p = wave_sum(f4.x * a4.x + f4.y * a4.y + f4.z * a4.z + f4.w * a4.w);
                    if (lane == 0)
                        gWork[b * DD + j] = 1.f / (1.f + expf(-(p + GXU[(size_t)bt * DD + j] + cb[j])));
                } else {                 // mem_out[j] = am.Wv[j] + bv[j]
                    float4 w4 = ((const float4*)(Wv + (size_t)j * DD))[lane];
                    float p = wave_sum(w4.x * a4.x + w4.y * a4.y + w4.z * a4.z + w4.w * a4.w);
                    if (lane == 0) out[(size_t)bt * DD + j] = p + bv[j];
                }
            }
        }

        barTarget += 16;
        batch_barrier(myctr, barTarget);             // barrier B

        // ---- update phase: apply top-8 row updates (owner chunks) ----
        float gv = gWork[b * DD + tid];
        for (int k = 0; k < TOPK; ++k) {
            int row = topI[k];
            bool mine = (row >> 7) == c;
            __syncthreads();
            if (mine && tid == 0) {
                int fs = flagslot[b * MM + row];
                int slot, wd = (fs != 0);
                if (!wd) {
                    slot = atomicAdd(&slotCnt[b], 1);
                    flagslot[b * MM + row] = slot + 1;
                    int cc = chunkCnt[b * 16 + c];
                    chunkCnt[b * 16 + c] = cc + 1;
                    listChunk[(b * 16 + c) * CHR + cc] = (slot << 7) | (row & 127);
                } else slot = fs - 1;
                slotK = slot; wasD = wd;
            }
            __syncthreads();
            if (mine) {
                float gathered = wasD ? dval[((size_t)b * 512 + slotK) * DD + tid]
                                      : memory0[(size_t)row * DD + tid];
                float u = (1.f - gv) * gathered + gv * xs[tid];
                dval[((size_t)b * 512 + slotK) * DD + tid] = u;
            }
        }
    }
}

extern "C" void kernel_launch(void* const* d_in, const int* in_sizes, int n_in,
                              void* d_out, int out_size, void* d_ws, size_t ws_size,
                              hipStream_t stream) {
    const float* x      = (const float*)d_in[0];
    const float* memory = (const float*)d_in[1];
    const float* Wq     = (const float*)d_in[2];
    const float* bq     = (const float*)d_in[3];
    const float* Wk     = (const float*)d_in[4];
    const float* bk     = (const float*)d_in[5];
    const float* Wv     = (const float*)d_in[6];
    const float* bv     = (const float*)d_in[7];
    const float* Wu     = (const float*)d_in[8];
    const float* bu     = (const float*)d_in[9];
    float* out = (float*)d_out;

    float* ws = (float*)d_ws;
    size_t o = 0;
    float* memT  = ws + o; o += (size_t)DD * MM;       // 524288
    float* WqT   = ws + o; o += DD * DD;
    float* WulT  = ws + o; o += DD * DD;
    float* F     = ws + o; o += DD * DD;
    float* cbv   = ws + o; o += DD;
    float* Q     = ws + o; o += (size_t)BB * SS * DD;
    float* QK    = ws + o; o += (size_t)BB * SS * DD;
    float* GXU   = ws + o; o += (size_t)BB * SS * DD;
    float* c0All = ws + o; o += BB * SS;
    float* dval  = ws + o; o += (size_t)BB * 512 * DD; // 8 MB
    float* pe    = ws + o; o += BB * 16;
    float* pam   = ws + o; o += (size_t)BB * 16 * DD;
    float* candV = ws + o; o += BB * 16 * TOPK;
    float* gWork = ws + o; o += BB * DD;
    int* candI     = (int*)(ws + o); o += BB * 16 * TOPK;
    int* zbase     = (int*)(ws + o);
    int* flagslot  = (int*)(ws + o); o += BB * MM;
    int* listChunk = (int*)(ws + o); o += BB * 16 * CHR;
    int* chunkCnt  = (int*)(ws + o); o += BB * 16;
    int* slotCnt   = (int*)(ws + o); o += BB;
    unsigned* ctr  = (unsigned*)(ws + o); o += BB * 16;
    const int nzero = BB * MM + BB * 16 * CHR + BB * 16 + BB + BB * 16;

    k_tr<<<dim3(DD / 32, MM / 32), 256, 0, stream>>>(memory, memT, DD, MM);
    k_tr<<<dim3(DD / 32, DD / 32), 256, 0, stream>>>(Wq, WqT, DD, DD);
    k_tr<<<dim3(DD / 32, DD / 32), 256, 0, stream>>>(Wu, WulT, 2 * DD, DD);
    k_gemv<<<BB * SS, 256, 0, stream>>>(x, WqT, bq, Q, nullptr, nullptr);
    k_gemv<<<BB * SS, 256, 0, stream>>>(Q, Wk, nullptr, QK, bk, c0All);
    k_gemv<<<BB * SS, 256, 0, stream>>>(x, WulT, bu, GXU, nullptr, nullptr);
    k_fuse<<<DD, 256, 0, stream>>>(Wu, Wv, bv, F, cbv);
    k_zero<<<(nzero + 255) / 256, 256, 0, stream>>>(zbase, nzero);
    k_persist<<<BB * NCH, 256, 0, stream>>>(x, memory, memT, QK, c0All, GXU, F, cbv,
                                            Wv, bv, dval, pe, pam, candV, candI, gWork,
                                            flagslot, listChunk, chunkCnt, slotCnt, ctr, out);
}

// Round 5
// 2600.494 us; speedup vs baseline: 1.2523x; 1.2523x over previous
//
#include <hip/hip_runtime.h>
#include <math.h>

#define BB 16
#define SS 64
#define MM 2048
#define DD 256
#define TOPK 8
#define NCH 16
#define CHR 128            // rows per chunk
#define SCALE 0.0625f      // 1/sqrt(256)

__device__ __forceinline__ float wave_sum(float p) {
    for (int o = 32; o; o >>= 1) p += __shfl_xor(p, o);
    return p;
}

__device__ __forceinline__ void wave_argmax(float& v, int& i) {
    for (int o = 32; o; o >>= 1) {
        float ov = __shfl_xor(v, o);
        int oi = __shfl_xor(i, o);
        if (ov > v || (ov == v && oi < i)) { v = ov; i = oi; }
    }
}

// generic 32x32-tiled transpose: dst[c][r] = src[r][c]; grid=(C/32, R/32), block=256
__global__ __launch_bounds__(256) void k_tr(const float* __restrict__ src, float* __restrict__ dst,
                                            int sld, int dld) {
    __shared__ float ts[32][33];
    int c0 = blockIdx.x * 32, r0 = blockIdx.y * 32;
    int xx = threadIdx.x & 31, yy = threadIdx.x >> 5;
    for (int i = 0; i < 4; ++i)
        ts[yy + 8 * i][xx] = src[(size_t)(r0 + yy + 8 * i) * sld + c0 + xx];
    __syncthreads();
    for (int i = 0; i < 4; ++i)
        dst[(size_t)(c0 + yy + 8 * i) * dld + r0 + xx] = ts[xx][yy + 8 * i];
}

// C[i][j] = sum_d A[i][d]*B[d][j] (+bias[j]); optional c0o[i] = Arow . bkv. grid = rows
__global__ __launch_bounds__(256) void k_gemv(const float* __restrict__ A, const float* __restrict__ B,
                                              const float* __restrict__ bias, float* __restrict__ C,
                                              const float* __restrict__ bkv, float* __restrict__ c0o) {
    const int i = blockIdx.x, tid = threadIdx.x;
    __shared__ float as[DD];
    as[tid] = A[(size_t)i * DD + tid];
    __syncthreads();
    float a0 = bias ? bias[tid] : 0.f, a1 = 0.f;
#pragma unroll 4
    for (int d = 0; d < DD; d += 2) {
        a0 = fmaf(as[d],     B[(size_t)d * DD + tid],       a0);
        a1 = fmaf(as[d + 1], B[(size_t)(d + 1) * DD + tid], a1);
    }
    C[(size_t)i * DD + tid] = a0 + a1;
    if (c0o && tid < 64) {
        float4 a4 = ((const float4*)as)[tid];
        float4 b4 = ((const float4*)bkv)[tid];
        float p = wave_sum(a4.x * b4.x + a4.y * b4.y + a4.z * b4.z + a4.w * b4.w);
        if (tid == 0) c0o[i] = p;
    }
}

// F[j][d] = sum_k Wu[j][256+k]*Wv[k][d];  cb[j] = sum_k bv[k]*Wu[j][256+k]. grid=256
__global__ __launch_bounds__(256) void k_fuse(const float* __restrict__ Wu, const float* __restrict__ Wv,
                                              const float* __restrict__ bv, float* __restrict__ F,
                                              float* __restrict__ cb) {
    const int j = blockIdx.x, tid = threadIdx.x;
    const float* wuh = Wu + (size_t)j * (2 * DD) + DD;
    float a0 = 0.f, a1 = 0.f;
#pragma unroll 4
    for (int k = 0; k < DD; k += 2) {
        a0 = fmaf(wuh[k],     Wv[(size_t)k * DD + tid],       a0);
        a1 = fmaf(wuh[k + 1], Wv[(size_t)(k + 1) * DD + tid], a1);
    }
    F[(size_t)j * DD + tid] = a0 + a1;
    if (tid < 64) {
        float4 b4 = ((const float4*)bv)[tid];
        float4 w4 = ((const float4*)wuh)[tid];
        float p = wave_sum(b4.x * w4.x + b4.y * w4.y + b4.z * w4.z + b4.w * w4.w);
        if (tid == 0) cb[j] = p;
    }
}

__global__ __launch_bounds__(256) void k_zero(int* __restrict__ p, int n) {
    int i = blockIdx.x * 256 + threadIdx.x;
    if (i < n) p[i] = 0;
}

// release add; RELAXED spin (no per-poll cache invalidate); one acquire fence at exit.
__device__ __forceinline__ void batch_barrier(unsigned* c, unsigned target) {
    __syncthreads();
    if (threadIdx.x == 0) {
        __hip_atomic_fetch_add(c, 1u, __ATOMIC_RELEASE, __HIP_MEMORY_SCOPE_AGENT);
        while (__hip_atomic_load(c, __ATOMIC_RELAXED, __HIP_MEMORY_SCOPE_AGENT) < target)
            __builtin_amdgcn_s_sleep(1);
        __builtin_amdgcn_fence(__ATOMIC_ACQUIRE, "agent");
    }
    __syncthreads();
}

__global__ __launch_bounds__(256) void k_persist(
    const float* __restrict__ x, const float* __restrict__ memory0,
    const float* __restrict__ memT, const float* __restrict__ QK,
    const float* __restrict__ c0All, const float* __restrict__ GXU,
    const float* __restrict__ F, const float* __restrict__ cb,
    const float* __restrict__ Wv, const float* __restrict__ bv,
    float* __restrict__ dval, float* __restrict__ pe, float* __restrict__ pam,
    float* __restrict__ candV, int* __restrict__ candI, float* __restrict__ gWork,
    int* __restrict__ flagslot, int* __restrict__ listChunk,
    int* __restrict__ chunkCnt, int* __restrict__ slotCnt,
    unsigned* __restrict__ ctr, float* __restrict__ out) {
    const int c = blockIdx.x & 15, b = blockIdx.x >> 4;
    const int tid = threadIdx.x, w = tid >> 6, lane = tid & 63;
    __shared__ float qks[DD], xs[DD], amS[DD];
    __shared__ float es[CHR];
    __shared__ float pPart[4][64];
    __shared__ float peS[16];
    __shared__ int topI[TOPK];
    __shared__ int slotArr[TOPK], wasArr[TOPK];
    unsigned* myctr = ctr + b * 16;     // 64B apart per batch
    unsigned barTarget = 0;

    for (int t = 0; t < SS; ++t) {
        const int bt = (b << 6) + t;
        qks[tid] = QK[(size_t)bt * DD + tid];
        xs[tid] = x[(size_t)bt * DD + tid];
        const float c0v = c0All[bt];
        const int nd = chunkCnt[b * 16 + c];
        __syncthreads();

        // ---- phase 1a: base scores over my 128 rows via memT (qk . memory0[m]) ----
        {
            const int h = w & 1, dh = w >> 1;
            const float* mptr = memT + (size_t)(dh * 128) * MM + c * CHR + h * 64 + lane;
            const float* qp = qks + dh * 128;
            float a0 = 0.f, a1 = 0.f, a2 = 0.f, a3 = 0.f;
#pragma unroll 8
            for (int d = 0; d < 128; d += 4) {
                a0 = fmaf(qp[d],     mptr[(size_t)d * MM],       a0);
                a1 = fmaf(qp[d + 1], mptr[(size_t)(d + 1) * MM], a1);
                a2 = fmaf(qp[d + 2], mptr[(size_t)(d + 2) * MM], a2);
                a3 = fmaf(qp[d + 3], mptr[(size_t)(d + 3) * MM], a3);
            }
            pPart[w][lane] = (a0 + a1) + (a2 + a3);
        }
        __syncthreads();
        if (tid < CHR) {
            int hh = tid >> 6, l = tid & 63;
            float s = pPart[hh][l] + pPart[hh + 2][l];
            es[tid] = expf((s + c0v) * SCALE);
        }
        __syncthreads();
        // phase 1b: dirty-row replacements e = exp((qk . cur[m] + c0)*scale)
        for (int i = w; i < nd; i += 4) {
            int packed = listChunk[(b * 16 + c) * CHR + i];
            int rl = packed & 127, slot = packed >> 7;
            float4 dv = ((const float4*)(dval + ((size_t)b * 512 + slot) * DD))[lane];
            float4 q4 = ((const float4*)qks)[lane];
            float p = wave_sum(dv.x * q4.x + dv.y * q4.y + dv.z * q4.z + dv.w * q4.w);
            if (lane == 0) es[rl] = expf((p + c0v) * SCALE);
        }
        __syncthreads();

        // phase 1c: weighted-mem partial, ALL threads, thread = column d
        {
            const float* m0 = memory0 + (size_t)c * CHR * DD + tid;
            float p = 0.f;
#pragma unroll 8
            for (int r = 0; r < CHR; ++r) p = fmaf(es[r], m0[(size_t)r * DD], p);
            for (int i = 0; i < nd; ++i) {
                int packed = listChunk[(b * 16 + c) * CHR + i];
                int rl = packed & 127, slot = packed >> 7;
                float e = es[rl];
                p += e * (dval[((size_t)b * 512 + slot) * DD + tid] - m0[(size_t)rl * DD]);
            }
            pam[(size_t)(b * 16 + c) * DD + tid] = p;
        }
        // phase 1d: denom (w0) + chunk-local top-8 candidates (w1)
        if (w == 0) {
            float v = es[lane] + es[lane + 64];
            float p = wave_sum(v);
            if (lane == 0) pe[b * 16 + c] = p;
        } else if (w == 1) {
            float v0 = es[lane], v1 = es[lane + 64];
            int i0 = lane, i1 = lane + 64;
            for (int k = 0; k < TOPK; ++k) {
                float bb = v0; int bi = i0;
                if (v1 > v0 || (v1 == v0 && i1 < i0)) { bb = v1; bi = i1; }
                wave_argmax(bb, bi);
                if (lane == 0) {
                    candV[(b * 16 + c) * TOPK + k] = bb;
                    candI[(b * 16 + c) * TOPK + k] = c * CHR + bi;
                }
                if (i0 == bi) v0 = -1e30f;
                if (i1 == bi) v1 = -1e30f;
            }
        }

        barTarget += 16;
        batch_barrier(myctr, barTarget);             // barrier A

        // ---- phase 2: am, gate slice + mem_out slice (5/9/9/9), top-8 merge (w0) ----
        if (tid < 16) peS[tid] = pe[b * 16 + tid];
        __syncthreads();
        float tot = 0.f;
#pragma unroll
        for (int i2 = 0; i2 < 16; ++i2) tot += peS[i2];
        float a = 0.f;
#pragma unroll
        for (int p2 = 0; p2 < 16; ++p2) a += pam[(size_t)(b * 16 + p2) * DD + tid];
        amS[tid] = a / tot;
        __syncthreads();

        if (w == 0) {                    // merge 128 candidates -> global top-8
            float v0 = candV[b * 128 + lane], v1 = candV[b * 128 + 64 + lane];
            int i0 = candI[b * 128 + lane], i1 = candI[b * 128 + 64 + lane];
            for (int k = 0; k < TOPK; ++k) {
                float bb = v0; int bi = i0;
                if (v1 > v0 || (v1 == v0 && i1 < i0)) { bb = v1; bi = i1; }
                wave_argmax(bb, bi);
                if (lane == 0) topI[k] = bi;
                if (i0 == bi) v0 = -1e30f;
                if (i1 == bi) v1 = -1e30f;
            }
        }
        {
            float4 a4 = ((const float4*)amS)[lane];
            const int tstart = (w == 0) ? 0 : 5 + (w - 1) * 9;
            const int tcnt = (w == 0) ? 5 : 9;
            for (int q = 0; q < tcnt; ++q) {
                int tt = tstart + q;
                int j = c * 16 + (tt & 15);
                if (tt < 16) {           // gate[j] = sigmoid(gxu + am.F[j] + cb[j])
                    float4 f4 = ((const float4*)(F + (size_t)j * DD))[lane];
                    float p = wave_sum(f4.x * a4.x + f4.y * a4.y + f4.z * a4.z + f4.w * a4.w);
                    if (lane == 0)
                        gWork[b * DD + j] = 1.f / (1.f + expf(-(p + GXU[(size_t)bt * DD + j] + cb[j])));
                } else {                 // mem_out[j] = am.Wv[j] + bv[j]
                    float4 w4 = ((const float4*)(Wv + (size_t)j * DD))[lane];
                    float p = wave_sum(w4.x * a4.x + w4.y * a4.y + w4.z * a4.z + w4.w * a4.w);
                    if (lane == 0) out[(size_t)bt * DD + j] = p + bv[j];
                }
            }
        }

        barTarget += 16;
        batch_barrier(myctr, barTarget);             // barrier B

        // ---- update: slot bookkeeping lanes 0..7 of w0, then one sync, then apply ----
        if (w == 0 && lane < TOPK) {
            int row = topI[lane];
            if ((row >> 7) == c) {
                int fs = flagslot[b * MM + row];
                int slot, wd = (fs != 0);
                if (!wd) {
                    slot = atomicAdd(&slotCnt[b], 1);
                    flagslot[b * MM + row] = slot + 1;
                    int cc = atomicAdd(&chunkCnt[b * 16 + c], 1);
                    listChunk[(b * 16 + c) * CHR + cc] = (slot << 7) | (row & 127);
                } else slot = fs - 1;
                slotArr[lane] = slot; wasArr[lane] = wd;
            }
        }
        __syncthreads();
        {
            float gv = gWork[b * DD + tid];
            float xv = xs[tid];
            for (int k = 0; k < TOPK; ++k) {
                int row = topI[k];
                if ((row >> 7) == c) {
                    size_t doff = ((size_t)b * 512 + slotArr[k]) * DD + tid;
                    float gathered = wasArr[k] ? dval[doff]
                                               : memory0[(size_t)row * DD + tid];
                    dval[doff] = (1.f - gv) * gathered + gv * xv;
                }
            }
        }
    }
}

extern "C" void kernel_launch(void* const* d_in, const int* in_sizes, int n_in,
                              void* d_out, int out_size, void* d_ws, size_t ws_size,
                              hipStream_t stream) {
    const float* x      = (const float*)d_in[0];
    const float* memory = (const float*)d_in[1];
    const float* Wq     = (const float*)d_in[2];
    const float* bq     = (const float*)d_in[3];
    const float* Wk     = (const float*)d_in[4];
    const float* bk     = (const float*)d_in[5];
    const float* Wv     = (const float*)d_in[6];
    const float* bv     = (const float*)d_in[7];
    const float* Wu     = (const float*)d_in[8];
    const float* bu     = (const float*)d_in[9];
    float* out = (float*)d_out;

    float* ws = (float*)d_ws;
    size_t o = 0;
    float* memT  = ws + o; o += (size_t)DD * MM;
    float* WqT   = ws + o; o += DD * DD;
    float* WulT  = ws + o; o += DD * DD;
    float* F     = ws + o; o += DD * DD;
    float* cbv   = ws + o; o += DD;
    float* Q     = ws + o; o += (size_t)BB * SS * DD;
    float* QK    = ws + o; o += (size_t)BB * SS * DD;
    float* GXU   = ws + o; o += (size_t)BB * SS * DD;
    float* c0All = ws + o; o += BB * SS;
    float* dval  = ws + o; o += (size_t)BB * 512 * DD; // 8 MB
    float* pe    = ws + o; o += BB * 16;
    float* pam   = ws + o; o += (size_t)BB * 16 * DD;
    float* candV = ws + o; o += BB * 16 * TOPK;
    float* gWork = ws + o; o += BB * DD;
    int* candI     = (int*)(ws + o); o += BB * 16 * TOPK;
    int* zbase     = (int*)(ws + o);
    int* flagslot  = (int*)(ws + o); o += BB * MM;
    int* listChunk = (int*)(ws + o); o += BB * 16 * CHR;
    int* chunkCnt  = (int*)(ws + o); o += BB * 16;
    int* slotCnt   = (int*)(ws + o); o += BB;
    unsigned* ctr  = (unsigned*)(ws + o); o += BB * 16;
    const int nzero = BB * MM + BB * 16 * CHR + BB * 16 + BB + BB * 16;

    k_tr<<<dim3(DD / 32, MM / 32), 256, 0, stream>>>(memory, memT, DD, MM);
    k_tr<<<dim3(DD / 32, DD / 32), 256, 0, stream>>>(Wq, WqT, DD, DD);
    k_tr<<<dim3(DD / 32, DD / 32), 256, 0, stream>>>(Wu, WulT, 2 * DD, DD);
    k_gemv<<<BB * SS, 256, 0, stream>>>(x, WqT, bq, Q, nullptr, nullptr);
    k_gemv<<<BB * SS, 256, 0, stream>>>(Q, Wk, nullptr, QK, bk, c0All);
    k_gemv<<<BB * SS, 256, 0, stream>>>(x, WulT, bu, GXU, nullptr, nullptr);
    k_fuse<<<DD, 256, 0, stream>>>(Wu, Wv, bv, F, cbv);
    k_zero<<<(nzero + 255) / 256, 256, 0, stream>>>(zbase, nzero);
    k_persist<<<BB * NCH, 256, 0, stream>>>(x, memory, memT, QK, c0All, GXU, F, cbv,
                                            Wv, bv, dval, pe, pam, candV, candI, gWork,
                                            flagslot, listChunk, chunkCnt, slotCnt, ctr, out);
}

// Round 6
// 2560.453 us; speedup vs baseline: 1.2719x; 1.0156x over previous
//
#include <hip/hip_runtime.h>
#include <math.h>

#define BB 16
#define SS 64
#define MM 2048
#define DD 256
#define TOPK 8
#define NCH 16
#define CHR 128            // rows per chunk
#define SCALE 0.0625f      // 1/sqrt(256)

__device__ __forceinline__ float wave_sum(float p) {
    for (int o = 32; o; o >>= 1) p += __shfl_xor(p, o);
    return p;
}

__device__ __forceinline__ void wave_argmax(float& v, int& i) {
    for (int o = 32; o; o >>= 1) {
        float ov = __shfl_xor(v, o);
        int oi = __shfl_xor(i, o);
        if (ov > v || (ov == v && oi < i)) { v = ov; i = oi; }
    }
}

// relaxed agent-scope atomics: bypass non-coherent per-XCD L2 (served at L3
// coherence point) WITHOUT any cache-invalidate fences.
__device__ __forceinline__ void astf(float* p, float v) {
    __hip_atomic_store(p, v, __ATOMIC_RELAXED, __HIP_MEMORY_SCOPE_AGENT);
}
__device__ __forceinline__ float aldf(const float* p) {
    return __hip_atomic_load(p, __ATOMIC_RELAXED, __HIP_MEMORY_SCOPE_AGENT);
}
__device__ __forceinline__ void asti(int* p, int v) {
    __hip_atomic_store(p, v, __ATOMIC_RELAXED, __HIP_MEMORY_SCOPE_AGENT);
}
__device__ __forceinline__ int aldi(const int* p) {
    return __hip_atomic_load(p, __ATOMIC_RELAXED, __HIP_MEMORY_SCOPE_AGENT);
}

// generic 32x32-tiled transpose: dst[c][r] = src[r][c]; grid=(C/32, R/32), block=256
__global__ __launch_bounds__(256) void k_tr(const float* __restrict__ src, float* __restrict__ dst,
                                            int sld, int dld) {
    __shared__ float ts[32][33];
    int c0 = blockIdx.x * 32, r0 = blockIdx.y * 32;
    int xx = threadIdx.x & 31, yy = threadIdx.x >> 5;
    for (int i = 0; i < 4; ++i)
        ts[yy + 8 * i][xx] = src[(size_t)(r0 + yy + 8 * i) * sld + c0 + xx];
    __syncthreads();
    for (int i = 0; i < 4; ++i)
        dst[(size_t)(c0 + yy + 8 * i) * dld + r0 + xx] = ts[xx][yy + 8 * i];
}

// C[i][j] = sum_d A[i][d]*B[d][j] (+bias[j]); optional c0o[i] = Arow . bkv. grid = rows
__global__ __launch_bounds__(256) void k_gemv(const float* __restrict__ A, const float* __restrict__ B,
                                              const float* __restrict__ bias, float* __restrict__ C,
                                              const float* __restrict__ bkv, float* __restrict__ c0o) {
    const int i = blockIdx.x, tid = threadIdx.x;
    __shared__ float as[DD];
    as[tid] = A[(size_t)i * DD + tid];
    __syncthreads();
    float a0 = bias ? bias[tid] : 0.f, a1 = 0.f;
#pragma unroll 4
    for (int d = 0; d < DD; d += 2) {
        a0 = fmaf(as[d],     B[(size_t)d * DD + tid],       a0);
        a1 = fmaf(as[d + 1], B[(size_t)(d + 1) * DD + tid], a1);
    }
    C[(size_t)i * DD + tid] = a0 + a1;
    if (c0o && tid < 64) {
        float4 a4 = ((const float4*)as)[tid];
        float4 b4 = ((const float4*)bkv)[tid];
        float p = wave_sum(a4.x * b4.x + a4.y * b4.y + a4.z * b4.z + a4.w * b4.w);
        if (tid == 0) c0o[i] = p;
    }
}

// F[j][d] = sum_k Wu[j][256+k]*Wv[k][d];  cb[j] = sum_k bv[k]*Wu[j][256+k]. grid=256
__global__ __launch_bounds__(256) void k_fuse(const float* __restrict__ Wu, const float* __restrict__ Wv,
                                              const float* __restrict__ bv, float* __restrict__ F,
                                              float* __restrict__ cb) {
    const int j = blockIdx.x, tid = threadIdx.x;
    const float* wuh = Wu + (size_t)j * (2 * DD) + DD;
    float a0 = 0.f, a1 = 0.f;
#pragma unroll 4
    for (int k = 0; k < DD; k += 2) {
        a0 = fmaf(wuh[k],     Wv[(size_t)k * DD + tid],       a0);
        a1 = fmaf(wuh[k + 1], Wv[(size_t)(k + 1) * DD + tid], a1);
    }
    F[(size_t)j * DD + tid] = a0 + a1;
    if (tid < 64) {
        float4 b4 = ((const float4*)bv)[tid];
        float4 w4 = ((const float4*)wuh)[tid];
        float p = wave_sum(b4.x * w4.x + b4.y * w4.y + b4.z * w4.z + b4.w * w4.w);
        if (tid == 0) cb[j] = p;
    }
}

__global__ __launch_bounds__(256) void k_zero(int* __restrict__ p, int n) {
    int i = blockIdx.x * 256 + threadIdx.x;
    if (i < n) p[i] = 0;
}

// fence-free barrier: __syncthreads drains vmcnt (sc1 stores committed to L3),
// then relaxed add + relaxed spin. NO cache invalidation -> L2 stays warm.
__device__ __forceinline__ void batch_barrier(unsigned* c, unsigned target) {
    __syncthreads();
    if (threadIdx.x == 0) {
        asm volatile("s_waitcnt vmcnt(0)" ::: "memory");
        __hip_atomic_fetch_add(c, 1u, __ATOMIC_RELAXED, __HIP_MEMORY_SCOPE_AGENT);
        while (__hip_atomic_load(c, __ATOMIC_RELAXED, __HIP_MEMORY_SCOPE_AGENT) < target)
            __builtin_amdgcn_s_sleep(1);
        asm volatile("" ::: "memory");
    }
    __syncthreads();
}

__global__ __launch_bounds__(256) void k_persist(
    const float* __restrict__ x, const float* __restrict__ memory0,
    const float* __restrict__ memT, const float* __restrict__ QK,
    const float* __restrict__ c0All, const float* __restrict__ GXU,
    const float* __restrict__ FT, const float* __restrict__ cb,
    const float* __restrict__ WvT, const float* __restrict__ bv,
    float* __restrict__ dval, float* __restrict__ pe2, float* __restrict__ pam2,
    float* __restrict__ candV2, int* __restrict__ candI2,
    int* __restrict__ flagslot, int* __restrict__ listChunk,
    int* __restrict__ chunkCnt, int* __restrict__ slotCnt,
    unsigned* __restrict__ ctr, float* __restrict__ out) {
    const int c = blockIdx.x & 15, b = blockIdx.x >> 4;
    const int tid = threadIdx.x, w = tid >> 6, lane = tid & 63;
    __shared__ float qks[DD], xs[DD], amS[DD], gs[DD];
    __shared__ float es[CHR];
    __shared__ float pPart[4][64];
    __shared__ float peS[16];
    __shared__ int topI[TOPK];
    __shared__ int slotArr[TOPK], wasArr[TOPK];
    unsigned* myctr = ctr + b * 16;     // 64B apart per batch
    unsigned barTarget = 0;

    for (int t = 0; t < SS; ++t) {
        const int bt = (b << 6) + t;
        const int par = t & 1;
        float* peP   = pe2   + (size_t)par * BB * 16;
        float* pamP  = pam2  + (size_t)par * BB * 16 * DD;
        float* candVP = candV2 + (size_t)par * BB * 128;
        int*   candIP = candI2 + (size_t)par * BB * 128;

        qks[tid] = QK[(size_t)bt * DD + tid];
        xs[tid] = x[(size_t)bt * DD + tid];
        const float c0v = c0All[bt];
        const int nd = aldi(&chunkCnt[b * 16 + c]);   // L1-bypass (RMW'd last step)
        __syncthreads();

        // ---- phase 1a: base scores over my 128 rows via memT (L2-hot) ----
        {
            const int h = w & 1, dh = w >> 1;
            const float* mptr = memT + (size_t)(dh * 128) * MM + c * CHR + h * 64 + lane;
            const float* qp = qks + dh * 128;
            float a0 = 0.f, a1 = 0.f, a2 = 0.f, a3 = 0.f;
#pragma unroll 8
            for (int d = 0; d < 128; d += 4) {
                a0 = fmaf(qp[d],     mptr[(size_t)d * MM],       a0);
                a1 = fmaf(qp[d + 1], mptr[(size_t)(d + 1) * MM], a1);
                a2 = fmaf(qp[d + 2], mptr[(size_t)(d + 2) * MM], a2);
                a3 = fmaf(qp[d + 3], mptr[(size_t)(d + 3) * MM], a3);
            }
            pPart[w][lane] = (a0 + a1) + (a2 + a3);
        }
        __syncthreads();
        if (tid < CHR) {
            int hh = tid >> 6, l = tid & 63;
            float s = pPart[hh][l] + pPart[hh + 2][l];
            es[tid] = expf((s + c0v) * SCALE);
        }
        __syncthreads();
        // phase 1b: dirty-row replacements (block-private dval, plain loads)
        for (int i = w; i < nd; i += 4) {
            int packed = listChunk[(b * 16 + c) * CHR + i];
            int rl = packed & 127, slot = packed >> 7;
            float4 dv = ((const float4*)(dval + ((size_t)b * 512 + slot) * DD))[lane];
            float4 q4 = ((const float4*)qks)[lane];
            float p = wave_sum(dv.x * q4.x + dv.y * q4.y + dv.z * q4.z + dv.w * q4.w);
            if (lane == 0) es[rl] = expf((p + c0v) * SCALE);
        }
        __syncthreads();

        // phase 1c: weighted-mem partial, thread = column d -> sc1 store
        {
            const float* m0 = memory0 + (size_t)c * CHR * DD + tid;
            float p = 0.f;
#pragma unroll 8
            for (int r = 0; r < CHR; ++r) p = fmaf(es[r], m0[(size_t)r * DD], p);
            for (int i = 0; i < nd; ++i) {
                int packed = listChunk[(b * 16 + c) * CHR + i];
                int rl = packed & 127, slot = packed >> 7;
                float e = es[rl];
                p += e * (dval[((size_t)b * 512 + slot) * DD + tid] - m0[(size_t)rl * DD]);
            }
            astf(&pamP[(size_t)(b * 16 + c) * DD + tid], p);
        }
        // phase 1d: denom (w0) + chunk-local top-8 candidates (w1) -> sc1 stores
        if (w == 0) {
            float v = es[lane] + es[lane + 64];
            float p = wave_sum(v);
            if (lane == 0) astf(&peP[b * 16 + c], p);
        } else if (w == 1) {
            float v0 = es[lane], v1 = es[lane + 64];
            int i0 = lane, i1 = lane + 64;
            for (int k = 0; k < TOPK; ++k) {
                float bb = v0; int bi = i0;
                if (v1 > v0 || (v1 == v0 && i1 < i0)) { bb = v1; bi = i1; }
                wave_argmax(bb, bi);
                if (lane == 0) {
                    astf(&candVP[b * 128 + c * TOPK + k], bb);
                    asti(&candIP[b * 128 + c * TOPK + k], c * CHR + bi);
                }
                if (i0 == bi) v0 = -1e30f;
                if (i1 == bi) v1 = -1e30f;
            }
        }

        barTarget += 16;
        batch_barrier(myctr, barTarget);             // the ONLY barrier per step

        // ---- phase 2: am (sc1 loads), topI merge (w0) || gate (w1-3), memout (c0) ----
        if (tid < 16) peS[tid] = aldf(&peP[b * 16 + tid]);
        __syncthreads();
        float tot = 0.f;
#pragma unroll
        for (int i2 = 0; i2 < 16; ++i2) tot += peS[i2];
        float a = 0.f;
#pragma unroll
        for (int p2 = 0; p2 < 16; ++p2) a += aldf(&pamP[(size_t)(b * 16 + p2) * DD + tid]);
        amS[tid] = a / tot;
        __syncthreads();

        if (w == 0) {                    // merge 128 candidates -> global top-8 (redundant/block)
            float v0 = aldf(&candVP[b * 128 + lane]), v1 = aldf(&candVP[b * 128 + 64 + lane]);
            int i0 = aldi(&candIP[b * 128 + lane]), i1 = aldi(&candIP[b * 128 + 64 + lane]);
            for (int k = 0; k < TOPK; ++k) {
                float bb = v0; int bi = i0;
                if (v1 > v0 || (v1 == v0 && i1 < i0)) { bb = v1; bi = i1; }
                wave_argmax(bb, bi);
                if (lane == 0) topI[k] = bi;
                if (i0 == bi) v0 = -1e30f;
                if (i1 == bi) v1 = -1e30f;
            }
        } else {                         // full gate vector, redundant per block (no comm)
            int j = tid - 64;            // 0..191
            float acc = GXU[(size_t)bt * DD + j] + cb[j];
#pragma unroll 4
            for (int d = 0; d < DD; ++d) acc = fmaf(amS[d], FT[(size_t)d * DD + j], acc);
            gs[j] = 1.f / (1.f + expf(-acc));
            if (j < 64) {
                int j2 = j + 192;
                float acc2 = GXU[(size_t)bt * DD + j2] + cb[j2];
#pragma unroll 4
                for (int d = 0; d < DD; ++d) acc2 = fmaf(amS[d], FT[(size_t)d * DD + j2], acc2);
                gs[j2] = 1.f / (1.f + expf(-acc2));
            }
        }
        if (c == 0) {                    // mem_out -> out, only one block per batch
            float acc = bv[tid];
#pragma unroll 4
            for (int d = 0; d < DD; ++d) acc = fmaf(amS[d], WvT[(size_t)d * DD + tid], acc);
            out[(size_t)bt * DD + tid] = acc;
        }
        __syncthreads();

        // ---- update: bookkeeping (w0 lanes 0..7), then apply (all, block-private) ----
        if (w == 0 && lane < TOPK) {
            int row = topI[lane];
            if ((row >> 7) == c) {
                int fs = flagslot[b * MM + row];
                int slot, wd = (fs != 0);
                if (!wd) {
                    slot = atomicAdd(&slotCnt[b], 1);
                    flagslot[b * MM + row] = slot + 1;
                    int cc = atomicAdd(&chunkCnt[b * 16 + c], 1);
                    listChunk[(b * 16 + c) * CHR + cc] = (slot << 7) | (row & 127);
                } else slot = fs - 1;
                slotArr[lane] = slot; wasArr[lane] = wd;
            }
        }
        __syncthreads();
        {
            float gv = gs[tid];
            float xv = xs[tid];
            for (int k = 0; k < TOPK; ++k) {
                int row = topI[k];
                if ((row >> 7) == c) {
                    size_t doff = ((size_t)b * 512 + slotArr[k]) * DD + tid;
                    float gathered = wasArr[k] ? dval[doff]
                                               : memory0[(size_t)row * DD + tid];
                    dval[doff] = (1.f - gv) * gathered + gv * xv;
                }
            }
        }
        __syncthreads();   // protect xs/qks/gs before next-iter overwrite
    }
}

extern "C" void kernel_launch(void* const* d_in, const int* in_sizes, int n_in,
                              void* d_out, int out_size, void* d_ws, size_t ws_size,
                              hipStream_t stream) {
    const float* x      = (const float*)d_in[0];
    const float* memory = (const float*)d_in[1];
    const float* Wq     = (const float*)d_in[2];
    const float* bq     = (const float*)d_in[3];
    const float* Wk     = (const float*)d_in[4];
    const float* bk     = (const float*)d_in[5];
    const float* Wv     = (const float*)d_in[6];
    const float* bv     = (const float*)d_in[7];
    const float* Wu     = (const float*)d_in[8];
    const float* bu     = (const float*)d_in[9];
    float* out = (float*)d_out;

    float* ws = (float*)d_ws;
    size_t o = 0;
    float* memT  = ws + o; o += (size_t)DD * MM;
    float* WqT   = ws + o; o += DD * DD;
    float* WulT  = ws + o; o += DD * DD;
    float* F     = ws + o; o += DD * DD;
    float* FT    = ws + o; o += DD * DD;
    float* WvT   = ws + o; o += DD * DD;
    float* cbv   = ws + o; o += DD;
    float* Q     = ws + o; o += (size_t)BB * SS * DD;
    float* QK    = ws + o; o += (size_t)BB * SS * DD;
    float* GXU   = ws + o; o += (size_t)BB * SS * DD;
    float* c0All = ws + o; o += BB * SS;
    float* dval  = ws + o; o += (size_t)BB * 512 * DD; // 8 MB
    float* pe2   = ws + o; o += 2 * BB * 16;
    float* pam2  = ws + o; o += (size_t)2 * BB * 16 * DD;
    float* candV2 = ws + o; o += 2 * BB * 128;
    int* candI2    = (int*)(ws + o); o += 2 * BB * 128;
    int* zbase     = (int*)(ws + o);
    int* flagslot  = (int*)(ws + o); o += BB * MM;
    int* listChunk = (int*)(ws + o); o += BB * 16 * CHR;
    int* chunkCnt  = (int*)(ws + o); o += BB * 16;
    int* slotCnt   = (int*)(ws + o); o += BB;
    unsigned* ctr  = (unsigned*)(ws + o); o += BB * 16;
    const int nzero = BB * MM + BB * 16 * CHR + BB * 16 + BB + BB * 16;

    k_tr<<<dim3(DD / 32, MM / 32), 256, 0, stream>>>(memory, memT, DD, MM);
    k_tr<<<dim3(DD / 32, DD / 32), 256, 0, stream>>>(Wq, WqT, DD, DD);
    k_tr<<<dim3(DD / 32, DD / 32), 256, 0, stream>>>(Wu, WulT, 2 * DD, DD);
    k_gemv<<<BB * SS, 256, 0, stream>>>(x, WqT, bq, Q, nullptr, nullptr);
    k_gemv<<<BB * SS, 256, 0, stream>>>(Q, Wk, nullptr, QK, bk, c0All);
    k_gemv<<<BB * SS, 256, 0, stream>>>(x, WulT, bu, GXU, nullptr, nullptr);
    k_fuse<<<DD, 256, 0, stream>>>(Wu, Wv, bv, F, cbv);
    k_tr<<<dim3(DD / 32, DD / 32), 256, 0, stream>>>(F, FT, DD, DD);
    k_tr<<<dim3(DD / 32, DD / 32), 256, 0, stream>>>(Wv, WvT, DD, DD);
    k_zero<<<(nzero + 255) / 256, 256, 0, stream>>>(zbase, nzero);
    k_persist<<<BB * NCH, 256, 0, stream>>>(x, memory, memT, QK, c0All, GXU, FT, cbv,
                                            WvT, bv, dval, pe2, pam2, candV2, candI2,
                                            flagslot, listChunk, chunkCnt, slotCnt, ctr, out);
}

// Round 9
// 1295.611 us; speedup vs baseline: 2.5136x; 1.9763x over previous
//
#include <hip/hip_runtime.h>
#include <math.h>

#define BB 16
#define SS 64
#define MM 2048
#define DD 256
#define TOPK 8
#define NCH 16
#define CHR 128            // rows per chunk
#define SCALE 0.0625f      // 1/sqrt(256)

__device__ __forceinline__ float wave_sum(float p) {
    for (int o = 32; o; o >>= 1) p += __shfl_xor(p, o);
    return p;
}

__device__ __forceinline__ void wave_argmax(float& v, int& i) {
    for (int o = 32; o; o >>= 1) {
        float ov = __shfl_xor(v, o);
        int oi = __shfl_xor(i, o);
        if (ov > v || (ov == v && oi < i)) { v = ov; i = oi; }
    }
}

// relaxed agent-scope atomics: bypass non-coherent per-XCD L2 (served at the
// coherence point) without any cache-invalidate fences.
__device__ __forceinline__ void astf(float* p, float v) {
    __hip_atomic_store(p, v, __ATOMIC_RELAXED, __HIP_MEMORY_SCOPE_AGENT);
}
__device__ __forceinline__ float aldf(const float* p) {
    return __hip_atomic_load(p, __ATOMIC_RELAXED, __HIP_MEMORY_SCOPE_AGENT);
}
__device__ __forceinline__ void asti(int* p, int v) {
    __hip_atomic_store(p, v, __ATOMIC_RELAXED, __HIP_MEMORY_SCOPE_AGENT);
}
__device__ __forceinline__ int aldi(const int* p) {
    return __hip_atomic_load(p, __ATOMIC_RELAXED, __HIP_MEMORY_SCOPE_AGENT);
}

// generic 32x32-tiled transpose: dst[c][r] = src[r][c]; grid=(C/32, R/32), block=256
__global__ __launch_bounds__(256) void k_tr(const float* __restrict__ src, float* __restrict__ dst,
                                            int sld, int dld) {
    __shared__ float ts[32][33];
    int c0 = blockIdx.x * 32, r0 = blockIdx.y * 32;
    int xx = threadIdx.x & 31, yy = threadIdx.x >> 5;
    for (int i = 0; i < 4; ++i)
        ts[yy + 8 * i][xx] = src[(size_t)(r0 + yy + 8 * i) * sld + c0 + xx];
    __syncthreads();
    for (int i = 0; i < 4; ++i)
        dst[(size_t)(c0 + yy + 8 * i) * dld + r0 + xx] = ts[xx][yy + 8 * i];
}

// C[i][j] = sum_d A[i][d]*B[d][j] (+bias[j]); optional c0o[i] = Arow . bkv. grid = rows
__global__ __launch_bounds__(256) void k_gemv(const float* __restrict__ A, const float* __restrict__ B,
                                              const float* __restrict__ bias, float* __restrict__ C,
                                              const float* __restrict__ bkv, float* __restrict__ c0o) {
    const int i = blockIdx.x, tid = threadIdx.x;
    __shared__ float as[DD];
    as[tid] = A[(size_t)i * DD + tid];
    __syncthreads();
    float a0 = bias ? bias[tid] : 0.f, a1 = 0.f;
#pragma unroll 4
    for (int d = 0; d < DD; d += 2) {
        a0 = fmaf(as[d],     B[(size_t)d * DD + tid],       a0);
        a1 = fmaf(as[d + 1], B[(size_t)(d + 1) * DD + tid], a1);
    }
    C[(size_t)i * DD + tid] = a0 + a1;
    if (c0o && tid < 64) {
        float4 a4 = ((const float4*)as)[tid];
        float4 b4 = ((const float4*)bkv)[tid];
        float p = wave_sum(a4.x * b4.x + a4.y * b4.y + a4.z * b4.z + a4.w * b4.w);
        if (tid == 0) c0o[i] = p;
    }
}

// F[j][d] = sum_k Wu[j][256+k]*Wv[k][d];  cb[j] = sum_k bv[k]*Wu[j][256+k]. grid=256
__global__ __launch_bounds__(256) void k_fuse(const float* __restrict__ Wu, const float* __restrict__ Wv,
                                              const float* __restrict__ bv, float* __restrict__ F,
                                              float* __restrict__ cb) {
    const int j = blockIdx.x, tid = threadIdx.x;
    const float* wuh = Wu + (size_t)j * (2 * DD) + DD;
    float a0 = 0.f, a1 = 0.f;
#pragma unroll 4
    for (int k = 0; k < DD; k += 2) {
        a0 = fmaf(wuh[k],     Wv[(size_t)k * DD + tid],       a0);
        a1 = fmaf(wuh[k + 1], Wv[(size_t)(k + 1) * DD + tid], a1);
    }
    F[(size_t)j * DD + tid] = a0 + a1;
    if (tid < 64) {
        float4 b4 = ((const float4*)bv)[tid];
        float4 w4 = ((const float4*)wuh)[tid];
        float p = wave_sum(b4.x * w4.x + b4.y * w4.y + b4.z * w4.z + b4.w * w4.w);
        if (tid == 0) cb[j] = p;
    }
}

__global__ __launch_bounds__(256) void k_zero(int* __restrict__ p, int n) {
    int i = blockIdx.x * 256 + threadIdx.x;
    if (i < n) p[i] = 0;
}

// fence-free barrier: __syncthreads drains vmcnt (sc stores committed),
// then relaxed add + relaxed spin. No cache invalidation -> L2 stays warm.
__device__ __forceinline__ void batch_barrier(unsigned* c, unsigned target) {
    __syncthreads();
    if (threadIdx.x == 0) {
        asm volatile("s_waitcnt vmcnt(0)" ::: "memory");
        __hip_atomic_fetch_add(c, 1u, __ATOMIC_RELAXED, __HIP_MEMORY_SCOPE_AGENT);
        while (__hip_atomic_load(c, __ATOMIC_RELAXED, __HIP_MEMORY_SCOPE_AGENT) < target)
            __builtin_amdgcn_s_sleep(1);
        asm volatile("" ::: "memory");
    }
    __syncthreads();
}

__global__ __launch_bounds__(1024) void k_persist(
    const float* __restrict__ x, const float* __restrict__ memory0,
    const float* __restrict__ memT, const float* __restrict__ QK,
    const float* __restrict__ c0All, const float* __restrict__ GXU,
    const float* __restrict__ F, const float* __restrict__ cb,
    const float* __restrict__ Wv, const float* __restrict__ bv,
    float* __restrict__ dval, float* __restrict__ pe2, float* __restrict__ pam2,
    float* __restrict__ candV2, int* __restrict__ candI2, float* __restrict__ gGlob,
    int* __restrict__ flagslot, int* __restrict__ listChunk,
    int* __restrict__ chunkCnt, int* __restrict__ slotCnt,
    unsigned* __restrict__ ctr, float* __restrict__ out) {
    // batch-per-XCD swizzle: all 16 chunk-blocks of batch b land on XCD b%8
    const int c = blockIdx.x >> 4, b = blockIdx.x & 15;
    const int tid = threadIdx.x, w = tid >> 6, lane = tid & 63;
    const int col = tid & 255, q = tid >> 8;          // 4 quarters x 256 cols
    __shared__ float qks[DD], xs[DD], amS[DD], gs[DD];
    __shared__ float es[CHR];
    __shared__ float pPart[8][CHR];
    __shared__ float cPart[4][DD];
    __shared__ float peS[16];
    __shared__ int topI[TOPK];
    __shared__ int slotArr[TOPK], wasArr[TOPK];
    unsigned* myctr = ctr + b * 16;     // 64B apart per batch
    unsigned barTarget = 0;

    for (int t = 0; t < SS; ++t) {
        const int bt = (b << 6) + t;
        const int par = t & 1;
        float* peP    = pe2   + (size_t)par * BB * 16;
        float* pamP   = pam2  + (size_t)par * BB * 16 * DD;
        float* candVP = candV2 + (size_t)par * BB * 128;
        int*   candIP = candI2 + (size_t)par * BB * 128;

        if (tid < DD) {
            qks[tid] = QK[(size_t)bt * DD + tid];
            xs[tid]  = x[(size_t)bt * DD + tid];
        }
        const float c0v = c0All[bt];
        const int nd = aldi(&chunkCnt[b * 16 + c]);   // RMW'd line -> L1-bypass read
        __syncthreads();

        // ---- 1a: base scores. thread: row r=(w&1)*64+lane, d in [ds*32, ds*32+32) ----
        {
            const int r = ((w & 1) << 6) + lane, ds = w >> 1;
            const float* mptr = memT + (size_t)(ds * 32) * MM + c * CHR + r;
            const float* qp = qks + ds * 32;
            float a0 = 0.f, a1 = 0.f, a2 = 0.f, a3 = 0.f;
#pragma unroll
            for (int d = 0; d < 32; d += 4) {
                a0 = fmaf(qp[d],     mptr[(size_t)d * MM],       a0);
                a1 = fmaf(qp[d + 1], mptr[(size_t)(d + 1) * MM], a1);
                a2 = fmaf(qp[d + 2], mptr[(size_t)(d + 2) * MM], a2);
                a3 = fmaf(qp[d + 3], mptr[(size_t)(d + 3) * MM], a3);
            }
            pPart[ds][r] = (a0 + a1) + (a2 + a3);
        }
        __syncthreads();
        if (tid < CHR) {
            float s = 0.f;
#pragma unroll
            for (int ds = 0; ds < 8; ++ds) s += pPart[ds][tid];
            es[tid] = expf((s + c0v) * SCALE);
        }
        __syncthreads();
        // ---- 1b: dirty-row score replacements (wave per dirty row) ----
        for (int i = w; i < nd; i += 16) {
            int packed = listChunk[(b * 16 + c) * CHR + i];
            int rl = packed & 127, slot = packed >> 7;
            float4 dv = ((const float4*)(dval + ((size_t)b * 512 + slot) * DD))[lane];
            float4 q4 = ((const float4*)qks)[lane];
            float p = wave_sum(dv.x * q4.x + dv.y * q4.y + dv.z * q4.z + dv.w * q4.w);
            if (lane == 0) es[rl] = expf((p + c0v) * SCALE);
        }
        __syncthreads();

        // ---- 1c: weighted-mem partial. quarter q does rows q*32..+32, col 'col' ----
        {
            const float* m0 = memory0 + ((size_t)c * CHR + q * 32) * DD + col;
            const float* eq = es + q * 32;
            float p = 0.f;
#pragma unroll 8
            for (int r = 0; r < 32; ++r) p = fmaf(eq[r], m0[(size_t)r * DD], p);
            for (int i = q; i < nd; i += 4) {    // dirty corrections, i = q mod 4
                int packed = listChunk[(b * 16 + c) * CHR + i];
                int rl = packed & 127, slot = packed >> 7;
                float e = es[rl];
                p += e * (dval[((size_t)b * 512 + slot) * DD + col]
                          - memory0[((size_t)c * CHR + rl) * DD + col]);
            }
            cPart[q][col] = p;
        }
        __syncthreads();
        if (tid < DD)                    // combine -> sc store
            astf(&pamP[(size_t)(b * 16 + c) * DD + tid],
                 cPart[0][tid] + cPart[1][tid] + cPart[2][tid] + cPart[3][tid]);
        if (w == 12) {                   // denom partial
            float p = wave_sum(es[lane] + es[lane + 64]);
            if (lane == 0) astf(&peP[b * 16 + c], p);
        } else if (w == 13) {            // chunk-local top-8 candidates
            float v0 = es[lane], v1 = es[lane + 64];
            int i0 = lane, i1 = lane + 64;
            for (int k = 0; k < TOPK; ++k) {
                float bb = v0; int bi = i0;
                if (v1 > v0 || (v1 == v0 && i1 < i0)) { bb = v1; bi = i1; }
                wave_argmax(bb, bi);
                if (lane == 0) {
                    astf(&candVP[b * 128 + c * TOPK + k], bb);
                    asti(&candIP[b * 128 + c * TOPK + k], c * CHR + bi);
                }
                if (i0 == bi) v0 = -1e30f;
                if (i1 == bi) v1 = -1e30f;
            }
        }

        barTarget += 16;
        batch_barrier(myctr, barTarget);             // barrier A

        // ---- phase 2: am, gate+memout (one output per wave), topI merge (w0) ----
        if (tid < 16) peS[tid] = aldf(&peP[b * 16 + tid]);
        {
            float a = 0.f;
#pragma unroll
            for (int p2 = q * 4; p2 < q * 4 + 4; ++p2)
                a += aldf(&pamP[(size_t)(b * 16 + p2) * DD + col]);
            cPart[q][col] = a;
        }
        __syncthreads();
        if (tid < DD) {
            float tot = 0.f;
#pragma unroll
            for (int i2 = 0; i2 < 16; ++i2) tot += peS[i2];
            amS[tid] = (cPart[0][tid] + cPart[1][tid] + cPart[2][tid] + cPart[3][tid]) / tot;
        }
        __syncthreads();
        {
            const int j = c * 16 + w;    // wave per output
            float4 a4 = ((const float4*)amS)[lane];
            float4 f4 = ((const float4*)(F + (size_t)j * DD))[lane];
            float pg = wave_sum(f4.x * a4.x + f4.y * a4.y + f4.z * a4.z + f4.w * a4.w);
            float4 w4 = ((const float4*)(Wv + (size_t)j * DD))[lane];
            float pv = wave_sum(w4.x * a4.x + w4.y * a4.y + w4.z * a4.z + w4.w * a4.w);
            if (lane == 0) {
                astf(&gGlob[b * DD + j],
                     1.f / (1.f + expf(-(pg + GXU[(size_t)bt * DD + j] + cb[j]))));
                out[(size_t)bt * DD + j] = pv + bv[j];
            }
        }
        if (w == 0) {                    // merge 128 candidates -> global top-8 (redundant)
            float v0 = aldf(&candVP[b * 128 + lane]), v1 = aldf(&candVP[b * 128 + 64 + lane]);
            int i0 = aldi(&candIP[b * 128 + lane]), i1 = aldi(&candIP[b * 128 + 64 + lane]);
            for (int k = 0; k < TOPK; ++k) {
                float bb = v0; int bi = i0;
                if (v1 > v0 || (v1 == v0 && i1 < i0)) { bb = v1; bi = i1; }
                wave_argmax(bb, bi);
                if (lane == 0) topI[k] = bi;
                if (i0 == bi) v0 = -1e30f;
                if (i1 == bi) v1 = -1e30f;
            }
        }

        barTarget += 16;
        batch_barrier(myctr, barTarget);             // barrier B

        // ---- update: gs gather + bookkeeping, sync, apply (block-private dval) ----
        if (tid < DD) gs[tid] = aldf(&gGlob[b * DD + tid]);
        if (w == 0 && lane < TOPK) {
            int row = topI[lane];
            if ((row >> 7) == c) {
                int fs = flagslot[b * MM + row];
                int slot, wd = (fs != 0);
                if (!wd) {
                    slot = atomicAdd(&slotCnt[b], 1);
                    flagslot[b * MM + row] = slot + 1;
                    int cc = atomicAdd(&chunkCnt[b * 16 + c], 1);
                    listChunk[(b * 16 + c) * CHR + cc] = (slot << 7) | (row & 127);
                } else slot = fs - 1;
                slotArr[lane] = slot; wasArr[lane] = wd;
            }
        }
        __syncthreads();
        {
            float xv = xs[col], gv = gs[col];
#pragma unroll
            for (int kk = q; kk < TOPK; kk += 4) {
                int row = topI[kk];
                if ((row >> 7) == c) {
                    size_t doff = ((size_t)b * 512 + slotArr[kk]) * DD + col;
                    float gathered = wasArr[kk] ? dval[doff]
                                               : memory0[(size_t)row * DD + col];
                    dval[doff] = (1.f - gv) * gathered + gv * xv;
                }
            }
        }
        __syncthreads();   // protect shared buffers before next-iter overwrite
    }
}

extern "C" void kernel_launch(void* const* d_in, const int* in_sizes, int n_in,
                              void* d_out, int out_size, void* d_ws, size_t ws_size,
                              hipStream_t stream) {
    const float* x      = (const float*)d_in[0];
    const float* memory = (const float*)d_in[1];
    const float* Wq     = (const float*)d_in[2];
    const float* bq     = (const float*)d_in[3];
    const float* Wk     = (const float*)d_in[4];
    const float* bk     = (const float*)d_in[5];
    const float* Wv     = (const float*)d_in[6];
    const float* bv     = (const float*)d_in[7];
    const float* Wu     = (const float*)d_in[8];
    const float* bu     = (const float*)d_in[9];
    float* out = (float*)d_out;

    float* ws = (float*)d_ws;
    size_t o = 0;
    float* memT  = ws + o; o += (size_t)DD * MM;
    float* WqT   = ws + o; o += DD * DD;
    float* WulT  = ws + o; o += DD * DD;
    float* F     = ws + o; o += DD * DD;
    float* cbv   = ws + o; o += DD;
    float* Q     = ws + o; o += (size_t)BB * SS * DD;
    float* QK    = ws + o; o += (size_t)BB * SS * DD;
    float* GXU   = ws + o; o += (size_t)BB * SS * DD;
    float* c0All = ws + o; o += BB * SS;
    float* dval  = ws + o; o += (size_t)BB * 512 * DD; // 8 MB
    float* pe2   = ws + o; o += 2 * BB * 16;
    float* pam2  = ws + o; o += (size_t)2 * BB * 16 * DD;
    float* candV2 = ws + o; o += 2 * BB * 128;
    float* gGlob  = ws + o; o += BB * DD;
    int* candI2    = (int*)(ws + o); o += 2 * BB * 128;
    int* zbase     = (int*)(ws + o);
    int* flagslot  = (int*)(ws + o); o += BB * MM;
    int* listChunk = (int*)(ws + o); o += BB * 16 * CHR;
    int* chunkCnt  = (int*)(ws + o); o += BB * 16;
    int* slotCnt   = (int*)(ws + o); o += BB;
    unsigned* ctr  = (unsigned*)(ws + o); o += BB * 16;
    const int nzero = BB * MM + BB * 16 * CHR + BB * 16 + BB + BB * 16;

    k_tr<<<dim3(DD / 32, MM / 32), 256, 0, stream>>>(memory, memT, DD, MM);
    k_tr<<<dim3(DD / 32, DD / 32), 256, 0, stream>>>(Wq, WqT, DD, DD);
    k_tr<<<dim3(DD / 32, DD / 32), 256, 0, stream>>>(Wu, WulT, 2 * DD, DD);
    k_gemv<<<BB * SS, 256, 0, stream>>>(x, WqT, bq, Q, nullptr, nullptr);
    k_gemv<<<BB * SS, 256, 0, stream>>>(Q, Wk, nullptr, QK, bk, c0All);
    k_gemv<<<BB * SS, 256, 0, stream>>>(x, WulT, bu, GXU, nullptr, nullptr);
    k_fuse<<<DD, 256, 0, stream>>>(Wu, Wv, bv, F, cbv);
    k_zero<<<(nzero + 255) / 256, 256, 0, stream>>>(zbase, nzero);
    k_persist<<<BB * NCH, 1024, 0, stream>>>(x, memory, memT, QK, c0All, GXU, F, cbv,
                                             Wv, bv, dval, pe2, pam2, candV2, candI2, gGlob,
                                             flagslot, listChunk, chunkCnt, slotCnt, ctr, out);
}